// Round 1
// baseline (909.953 us; speedup 1.0000x reference)
//
#include <hip/hip_runtime.h>
#include <hip/hip_bf16.h>

#define T_STEPS 512
#define BATCH   256
#define FDIM    256
#define H1      128
#define H2      64
#define OUT_N   5

__device__ __forceinline__ float sigmf(float x) {
    return 1.0f / (1.0f + __expf(-x));
}
__device__ __forceinline__ float tanh_fast(float x) {
    float cx = fminf(15.0f, fmaxf(-15.0f, x));
    float e  = __expf(2.0f * cx);
    return (e - 1.0f) / (e + 1.0f);
}

// ---------------------------------------------------------------------------
// Kernel 1: xp1[t][g] = b_ih1[g] + sum_f x[t,255,f] * w_ih1[g,f]
// One block per t, 384 threads (one per gate-row g). x row staged in LDS.
// ---------------------------------------------------------------------------
__global__ __launch_bounds__(384) void xp1_kernel(
    const float* __restrict__ x,
    const float* __restrict__ w_ih1,
    const float* __restrict__ b_ih1,
    float* __restrict__ xp1)
{
    __shared__ float xrow[FDIM];
    const int t = blockIdx.x;
    const float* xr = x + (size_t)t * BATCH * FDIM + (size_t)(BATCH - 1) * FDIM;
    if (threadIdx.x < FDIM / 4) {
        ((float4*)xrow)[threadIdx.x] = ((const float4*)xr)[threadIdx.x];
    }
    __syncthreads();
    const int g = threadIdx.x;
    const float* w = w_ih1 + (size_t)g * FDIM;
    float acc = b_ih1[g];
    #pragma unroll 8
    for (int f = 0; f < FDIM; f += 4) {
        float4 wv = *(const float4*)(w + f);
        acc = fmaf(wv.x, xrow[f + 0], acc);
        acc = fmaf(wv.y, xrow[f + 1], acc);
        acc = fmaf(wv.z, xrow[f + 2], acc);
        acc = fmaf(wv.w, xrow[f + 3], acc);
    }
    xp1[t * (3 * H1) + g] = acc;
}

// ---------------------------------------------------------------------------
// Kernel 2: the sequential 2-layer GRU recurrence for the single batch row.
// 1 block, 512 threads (8 waves on one CU). Weights register-resident.
//
// Phase 1 (layer 1): tid = 4*j1 + s1. Thread owns K-slice (32 of 128) of the
//   three W_hh1 rows {j1, 128+j1, 256+j1}; quad shfl_xor reduce; lane s1==0
//   does the gates and writes h1buf[p^1][j1].
// Phase 2 (layer 2): tid = 8*j2 + s2. Thread owns K-slices of three W_ih2
//   rows (16 of 128) and three W_hh2 rows (8 of 64); 8-lane shfl_xor reduce;
//   lane s2==0 does gates, writes h2buf[p^1][j2] and h2_all[t][j2].
//
// K-slices are interleaved (k = s*4 + stride*c + i) so each wave-wide
// ds_read_b128 covers consecutive floats -> no LDS bank conflicts.
// Two barriers per step. xp1 row for t+1 prefetched one step ahead.
// ---------------------------------------------------------------------------
__global__ __launch_bounds__(512) void gru_seq_kernel(
    const float* __restrict__ xp1,
    const float* __restrict__ w_hh1, const float* __restrict__ b_hh1,
    const float* __restrict__ w_ih2, const float* __restrict__ b_ih2,
    const float* __restrict__ w_hh2, const float* __restrict__ b_hh2,
    float* __restrict__ h2_all)
{
    const int tid = threadIdx.x;
    const int j1 = tid >> 2, s1 = tid & 3;
    const int j2 = tid >> 3, s2 = tid & 7;

    // ---- phase-1 weights: W_hh1 rows j1, H1+j1, 2H1+j1; slice k = s1*4+16c+i
    float w1r[32], w1z[32], w1n[32];
    {
        const float* br = w_hh1 + (size_t)(         j1) * H1;
        const float* bz = w_hh1 + (size_t)(H1     + j1) * H1;
        const float* bn = w_hh1 + (size_t)(2 * H1 + j1) * H1;
        #pragma unroll
        for (int c = 0; c < 8; c++) {
            const int k = s1 * 4 + 16 * c;
            *(float4*)&w1r[4 * c] = *(const float4*)&br[k];
            *(float4*)&w1z[4 * c] = *(const float4*)&bz[k];
            *(float4*)&w1n[4 * c] = *(const float4*)&bn[k];
        }
    }
    // ---- phase-2 weights: W_ih2 slice k = s2*4+32c+i (c<4); W_hh2 c<2
    float w2xr[16], w2xz[16], w2xn[16];
    float w2hr[8],  w2hz[8],  w2hn[8];
    {
        const float* br = w_ih2 + (size_t)(         j2) * H1;
        const float* bz = w_ih2 + (size_t)(H2     + j2) * H1;
        const float* bn = w_ih2 + (size_t)(2 * H2 + j2) * H1;
        #pragma unroll
        for (int c = 0; c < 4; c++) {
            const int k = s2 * 4 + 32 * c;
            *(float4*)&w2xr[4 * c] = *(const float4*)&br[k];
            *(float4*)&w2xz[4 * c] = *(const float4*)&bz[k];
            *(float4*)&w2xn[4 * c] = *(const float4*)&bn[k];
        }
        const float* hr = w_hh2 + (size_t)(         j2) * H2;
        const float* hz = w_hh2 + (size_t)(H2     + j2) * H2;
        const float* hn = w_hh2 + (size_t)(2 * H2 + j2) * H2;
        #pragma unroll
        for (int c = 0; c < 2; c++) {
            const int k = s2 * 4 + 32 * c;
            *(float4*)&w2hr[4 * c] = *(const float4*)&hr[k];
            *(float4*)&w2hz[4 * c] = *(const float4*)&hz[k];
            *(float4*)&w2hn[4 * c] = *(const float4*)&hn[k];
        }
    }
    const float bh1r = b_hh1[j1], bh1z = b_hh1[H1 + j1], bh1n = b_hh1[2 * H1 + j1];
    const float bi2r = b_ih2[j2], bi2z = b_ih2[H2 + j2], bi2n = b_ih2[2 * H2 + j2];
    const float bh2r = b_hh2[j2], bh2z = b_hh2[H2 + j2], bh2n = b_hh2[2 * H2 + j2];

    __shared__ float h1buf[2][H1];
    __shared__ float h2buf[2][H2];
    if (tid < H1) h1buf[0][tid] = 0.0f;
    if (tid < H2) h2buf[0][tid] = 0.0f;

    // prefetch xp1 row for t=0
    float nxr = xp1[j1], nxz = xp1[H1 + j1], nxn = xp1[2 * H1 + j1];
    __syncthreads();

    for (int t = 0; t < T_STEPS; ++t) {
        const int p = t & 1;
        const float xr = nxr, xz = nxz, xn = nxn;
        if (t + 1 < T_STEPS) {
            const float* nx = xp1 + (size_t)(t + 1) * (3 * H1);
            nxr = nx[j1]; nxz = nx[H1 + j1]; nxn = nx[2 * H1 + j1];
        }

        // ------------------ phase 1: layer-1 recurrent matvec + gates -------
        const float* h1rd = h1buf[p];
        float hreg[32];
        #pragma unroll
        for (int c = 0; c < 8; c++)
            *(float4*)&hreg[4 * c] = *(const float4*)&h1rd[s1 * 4 + 16 * c];
        float ar = 0.f, az = 0.f, an = 0.f;
        #pragma unroll
        for (int k = 0; k < 32; k++) {
            ar = fmaf(w1r[k], hreg[k], ar);
            az = fmaf(w1z[k], hreg[k], az);
            an = fmaf(w1n[k], hreg[k], an);
        }
        ar += __shfl_xor(ar, 1); az += __shfl_xor(az, 1); an += __shfl_xor(an, 1);
        ar += __shfl_xor(ar, 2); az += __shfl_xor(az, 2); an += __shfl_xor(an, 2);
        const float h1old = h1rd[j1];
        if (s1 == 0) {
            const float r = sigmf(xr + ar + bh1r);
            const float z = sigmf(xz + az + bh1z);
            const float n = tanh_fast(xn + r * (an + bh1n));
            h1buf[p ^ 1][j1] = (1.0f - z) * n + z * h1old;
        }
        __syncthreads();

        // ------------------ phase 2: layer-2 input+recurrent matvec + gates -
        const float* h1n_rd = h1buf[p ^ 1];
        const float* h2rd   = h2buf[p];
        float g1[16], g2[8];
        #pragma unroll
        for (int c = 0; c < 4; c++)
            *(float4*)&g1[4 * c] = *(const float4*)&h1n_rd[s2 * 4 + 32 * c];
        #pragma unroll
        for (int c = 0; c < 2; c++)
            *(float4*)&g2[4 * c] = *(const float4*)&h2rd[s2 * 4 + 32 * c];
        float axr = 0.f, axz = 0.f, axn = 0.f, ahr = 0.f, ahz = 0.f, ahn = 0.f;
        #pragma unroll
        for (int k = 0; k < 16; k++) {
            axr = fmaf(w2xr[k], g1[k], axr);
            axz = fmaf(w2xz[k], g1[k], axz);
            axn = fmaf(w2xn[k], g1[k], axn);
        }
        #pragma unroll
        for (int k = 0; k < 8; k++) {
            ahr = fmaf(w2hr[k], g2[k], ahr);
            ahz = fmaf(w2hz[k], g2[k], ahz);
            ahn = fmaf(w2hn[k], g2[k], ahn);
        }
        #pragma unroll
        for (int m = 1; m < 8; m <<= 1) {
            axr += __shfl_xor(axr, m); axz += __shfl_xor(axz, m); axn += __shfl_xor(axn, m);
            ahr += __shfl_xor(ahr, m); ahz += __shfl_xor(ahz, m); ahn += __shfl_xor(ahn, m);
        }
        const float h2old = h2rd[j2];
        if (s2 == 0) {
            const float r = sigmf(axr + bi2r + ahr + bh2r);
            const float z = sigmf(axz + bi2z + ahz + bh2z);
            const float n = tanh_fast(axn + bi2n + r * (ahn + bh2n));
            const float hn = (1.0f - z) * n + z * h2old;
            h2buf[p ^ 1][j2] = hn;
            h2_all[t * H2 + j2] = hn;
        }
        __syncthreads();
    }
}

// ---------------------------------------------------------------------------
// Kernel 3: out[t][o] = lin_b[o] + sum_j h2_all[t][j] * lin_w[o][j]
// ---------------------------------------------------------------------------
__global__ __launch_bounds__(256) void head_kernel(
    const float* __restrict__ h2_all,
    const float* __restrict__ lin_w,
    const float* __restrict__ lin_b,
    float* __restrict__ out)
{
    const int t = blockIdx.x * blockDim.x + threadIdx.x;
    if (t >= T_STEPS) return;
    const float* h = h2_all + t * H2;
    #pragma unroll
    for (int o = 0; o < OUT_N; o++) {
        float acc = lin_b[o];
        const float* w = lin_w + o * H2;
        #pragma unroll
        for (int j = 0; j < H2; j += 4) {
            float4 wv = *(const float4*)(w + j);
            float4 hv = *(const float4*)(h + j);
            acc = fmaf(wv.x, hv.x, acc);
            acc = fmaf(wv.y, hv.y, acc);
            acc = fmaf(wv.z, hv.z, acc);
            acc = fmaf(wv.w, hv.w, acc);
        }
        out[t * OUT_N + o] = acc;
    }
}

extern "C" void kernel_launch(void* const* d_in, const int* in_sizes, int n_in,
                              void* d_out, int out_size, void* d_ws, size_t ws_size,
                              hipStream_t stream) {
    const float* x     = (const float*)d_in[0];
    const float* w_ih1 = (const float*)d_in[1];
    const float* w_hh1 = (const float*)d_in[2];
    const float* b_ih1 = (const float*)d_in[3];
    const float* b_hh1 = (const float*)d_in[4];
    const float* w_ih2 = (const float*)d_in[5];
    const float* w_hh2 = (const float*)d_in[6];
    const float* b_ih2 = (const float*)d_in[7];
    const float* b_hh2 = (const float*)d_in[8];
    const float* lin_w = (const float*)d_in[9];
    const float* lin_b = (const float*)d_in[10];
    float* out = (float*)d_out;

    float* xp1    = (float*)d_ws;                  // 512*384 floats
    float* h2_all = xp1 + T_STEPS * 3 * H1;        // 512*64 floats

    xp1_kernel<<<T_STEPS, 3 * H1, 0, stream>>>(x, w_ih1, b_ih1, xp1);
    gru_seq_kernel<<<1, 512, 0, stream>>>(xp1, w_hh1, b_hh1,
                                          w_ih2, b_ih2, w_hh2, b_hh2, h2_all);
    head_kernel<<<(T_STEPS + 255) / 256, 256, 0, stream>>>(h2_all, lin_w, lin_b, out);
}

// Round 2
// 690.605 us; speedup vs baseline: 1.3176x; 1.3176x over previous
//
#include <hip/hip_runtime.h>
#include <hip/hip_bf16.h>

#define T_STEPS 512
#define BATCH   256
#define FDIM    256
#define H1      128
#define H2      64
#define OUT_N   5
#define CAT     (H1 + H2)     // 192
#define LOG2E   1.4426950408889634f

#if __has_builtin(__builtin_amdgcn_exp2f)
#define EXP2F(x) __builtin_amdgcn_exp2f(x)
#else
#define EXP2F(x) exp2f(x)
#endif
#if __has_builtin(__builtin_amdgcn_rcpf)
#define RCPF(x) __builtin_amdgcn_rcpf(x)
#else
#define RCPF(x) (1.0f / (x))
#endif

// v + v(lane XOR pattern) via DPP quad_perm. 0xB1 = xor1, 0x4E = xor2.
template<int CTRL>
__device__ __forceinline__ float dpp_add(float v) {
    int s = __builtin_amdgcn_update_dpp(0, __float_as_int(v), CTRL, 0xF, 0xF, true);
    return v + __int_as_float(s);
}
// v + v(lane XOR 4) via ds_swizzle butterfly (all-lane valid).
__device__ __forceinline__ float swz_add_xor4(float v) {
    int s = __builtin_amdgcn_ds_swizzle(__float_as_int(v), 0x101F);
    return v + __int_as_float(s);
}
// a = -log2e * x  ->  sigmoid(x)
__device__ __forceinline__ float sig_scaled(float a) {
    return RCPF(1.0f + EXP2F(a));
}
// a = 2*log2e * u ->  tanh(u)   (inf-safe: exp2->inf => rcp->0 => 1)
__device__ __forceinline__ float tanh_scaled(float a) {
    return fmaf(-2.0f, RCPF(EXP2F(a) + 1.0f), 1.0f);
}

// ---------------------------------------------------------------------------
// Kernel 1: xp[t][g] = scale_g * (b_ih1[g] + badd_g + sum_f x[t,255,f]*w_ih1[g,f])
// badd = b_hh1 for r,z gates (folded), 0 for n. scale = -log2e (r,z), +2log2e (n).
// ---------------------------------------------------------------------------
__global__ __launch_bounds__(384) void xp1_kernel(
    const float* __restrict__ x,
    const float* __restrict__ w_ih1,
    const float* __restrict__ b_ih1,
    const float* __restrict__ b_hh1,
    float* __restrict__ xp)
{
    __shared__ float xrow[FDIM];
    const int t = blockIdx.x;
    const float* xr = x + (size_t)t * BATCH * FDIM + (size_t)(BATCH - 1) * FDIM;
    if (threadIdx.x < FDIM / 4) {
        ((float4*)xrow)[threadIdx.x] = ((const float4*)xr)[threadIdx.x];
    }
    __syncthreads();
    const int g = threadIdx.x;
    const float* w = w_ih1 + (size_t)g * FDIM;
    float acc = b_ih1[g];
    #pragma unroll 8
    for (int f = 0; f < FDIM; f += 4) {
        float4 wv = *(const float4*)(w + f);
        acc = fmaf(wv.x, xrow[f + 0], acc);
        acc = fmaf(wv.y, xrow[f + 1], acc);
        acc = fmaf(wv.z, xrow[f + 2], acc);
        acc = fmaf(wv.w, xrow[f + 3], acc);
    }
    const bool isN = (g >= 2 * H1);
    const float badd  = isN ? 0.0f : b_hh1[g];
    const float scale = isN ? (2.0f * LOG2E) : (-LOG2E);
    xp[t * (3 * H1) + g] = scale * (acc + badd);
}

// ---------------------------------------------------------------------------
// Kernel 2: sequential 2-layer GRU, software-pipelined: at iter k, layer 1
// produces h1[k] while layer 2 produces h2[k-1]. Both read cat[prev] only and
// write cat[cur] only -> ONE barrier per iteration. 512 thr = 8 waves, 1 CU.
// Weights register-resident (launch_bounds(512,2) -> 256 VGPR cap), pre-scaled
// by -log2e / +2log2e so gates are exp2+rcp only.
//
// L1 mapping: tid = 4*j1+s1, K-slice k = s1*4+16c (c<8) of W_hh1 rows
//   {j1, 128+j1, 256+j1}. Quad DPP reduce (xor1,xor2) -> all lanes valid.
// L2 mapping: tid = 8*j2+s2, concat-K [h1;h2] (192), slice k = s2*4+32c (c<6)
//   of concat rows [W_ih2[g] | W_hh2[g]]. r,z accumulate over full concat;
//   n keeps x-part (c<4) and h-part (c>=4) separate. Reduce: DPP xor1,xor2 +
//   ds_swizzle xor4.
// ---------------------------------------------------------------------------
__global__ __launch_bounds__(512, 2) void gru_seq_kernel(
    const float* __restrict__ xp,
    const float* __restrict__ w_hh1, const float* __restrict__ b_hh1,
    const float* __restrict__ w_ih2, const float* __restrict__ b_ih2,
    const float* __restrict__ w_hh2, const float* __restrict__ b_hh2,
    float* __restrict__ h2_all)
{
    const int tid = threadIdx.x;
    const int j1 = tid >> 2, s1 = tid & 3;
    const int j2 = tid >> 3, s2 = tid & 7;
    const float sRZ = -LOG2E, sN = 2.0f * LOG2E;

    // ---- L1 weights (scaled), slice k = s1*4 + 16c ----
    float w1r[32], w1z[32], w1n[32];
    {
        const float* br = w_hh1 + (size_t)(         j1) * H1;
        const float* bz = w_hh1 + (size_t)(H1     + j1) * H1;
        const float* bn = w_hh1 + (size_t)(2 * H1 + j1) * H1;
        #pragma unroll
        for (int c = 0; c < 8; c++) {
            const int kk = (s1 << 2) + 16 * c;
            float4 vr = *(const float4*)(br + kk);
            float4 vz = *(const float4*)(bz + kk);
            float4 vn = *(const float4*)(bn + kk);
            w1r[4*c+0] = sRZ*vr.x; w1r[4*c+1] = sRZ*vr.y; w1r[4*c+2] = sRZ*vr.z; w1r[4*c+3] = sRZ*vr.w;
            w1z[4*c+0] = sRZ*vz.x; w1z[4*c+1] = sRZ*vz.y; w1z[4*c+2] = sRZ*vz.z; w1z[4*c+3] = sRZ*vz.w;
            w1n[4*c+0] = sN *vn.x; w1n[4*c+1] = sN *vn.y; w1n[4*c+2] = sN *vn.z; w1n[4*c+3] = sN *vn.w;
        }
    }
    // ---- L2 concat weights (scaled), slice k = s2*4 + 32c ----
    float w2r[24], w2z[24], w2n[24];
    {
        const float* ir  = w_ih2 + (size_t)(         j2) * H1;
        const float* iz  = w_ih2 + (size_t)(H2     + j2) * H1;
        const float* inn = w_ih2 + (size_t)(2 * H2 + j2) * H1;
        const float* hr  = w_hh2 + (size_t)(         j2) * H2;
        const float* hz  = w_hh2 + (size_t)(H2     + j2) * H2;
        const float* hn  = w_hh2 + (size_t)(2 * H2 + j2) * H2;
        #pragma unroll
        for (int c = 0; c < 6; c++) {
            const int kk = (s2 << 2) + 32 * c;
            const bool lo = (kk < H1);
            float4 vr = *(const float4*)(lo ? ir  + kk : hr + (kk - H1));
            float4 vz = *(const float4*)(lo ? iz  + kk : hz + (kk - H1));
            float4 vn = *(const float4*)(lo ? inn + kk : hn + (kk - H1));
            w2r[4*c+0] = sRZ*vr.x; w2r[4*c+1] = sRZ*vr.y; w2r[4*c+2] = sRZ*vr.z; w2r[4*c+3] = sRZ*vr.w;
            w2z[4*c+0] = sRZ*vz.x; w2z[4*c+1] = sRZ*vz.y; w2z[4*c+2] = sRZ*vz.z; w2z[4*c+3] = sRZ*vz.w;
            w2n[4*c+0] = sN *vn.x; w2n[4*c+1] = sN *vn.y; w2n[4*c+2] = sN *vn.z; w2n[4*c+3] = sN *vn.w;
        }
    }
    const float bh1n_s = sN * b_hh1[2 * H1 + j1];
    const float b2r_s  = sRZ * (b_ih2[j2]          + b_hh2[j2]);
    const float b2z_s  = sRZ * (b_ih2[H2 + j2]     + b_hh2[H2 + j2]);
    const float b2xn_s = sN  *  b_ih2[2 * H2 + j2];
    const float b2hn_s = sN  *  b_hh2[2 * H2 + j2];

    __shared__ float cat[2][CAT];
    if (tid < CAT) { cat[0][tid] = 0.0f; cat[1][tid] = 0.0f; }

    // prefetch xp row 0
    float cxr = xp[j1], cxz = xp[H1 + j1], cxn = xp[2 * H1 + j1];
    __syncthreads();

    for (int k = 0; k <= T_STEPS; ++k) {
        const int pc = k & 1, pp = pc ^ 1;
        const float* rp = cat[pp];
        float* wp = cat[pc];

        const float xr = cxr, xz = cxz, xn = cxn;
        if (k + 1 < T_STEPS) {
            const float* nx = xp + (size_t)(k + 1) * (3 * H1);
            cxr = nx[j1]; cxz = nx[H1 + j1]; cxn = nx[2 * H1 + j1];
        }

        // ---------------- L1: h1[k] = f(h1[k-1], xp[k]) ----------------
        float ar = 0.f, az = 0.f, an = 0.f;
        {
            const float* hp = rp + (s1 << 2);
            #pragma unroll
            for (int c = 0; c < 8; c++) {
                float4 h4 = *(const float4*)(hp + 16 * c);
                ar = fmaf(w1r[4*c+0], h4.x, ar); az = fmaf(w1z[4*c+0], h4.x, az); an = fmaf(w1n[4*c+0], h4.x, an);
                ar = fmaf(w1r[4*c+1], h4.y, ar); az = fmaf(w1z[4*c+1], h4.y, az); an = fmaf(w1n[4*c+1], h4.y, an);
                ar = fmaf(w1r[4*c+2], h4.z, ar); az = fmaf(w1z[4*c+2], h4.z, az); an = fmaf(w1n[4*c+2], h4.z, an);
                ar = fmaf(w1r[4*c+3], h4.w, ar); az = fmaf(w1z[4*c+3], h4.w, az); an = fmaf(w1n[4*c+3], h4.w, an);
            }
        }
        // ---------------- L2: h2[k-1] = g(h2[k-2], h1[k-1]) ------------
        float a2r = 0.f, a2z = 0.f, axn = 0.f, ahn = 0.f;
        {
            const float* gp = rp + (s2 << 2);
            #pragma unroll
            for (int c = 0; c < 6; c++) {
                float4 h4 = *(const float4*)(gp + 32 * c);
                a2r = fmaf(w2r[4*c+0], h4.x, a2r); a2z = fmaf(w2z[4*c+0], h4.x, a2z);
                a2r = fmaf(w2r[4*c+1], h4.y, a2r); a2z = fmaf(w2z[4*c+1], h4.y, a2z);
                a2r = fmaf(w2r[4*c+2], h4.z, a2r); a2z = fmaf(w2z[4*c+2], h4.z, a2z);
                a2r = fmaf(w2r[4*c+3], h4.w, a2r); a2z = fmaf(w2z[4*c+3], h4.w, a2z);
                if (c < 4) {
                    axn = fmaf(w2n[4*c+0], h4.x, axn); axn = fmaf(w2n[4*c+1], h4.y, axn);
                    axn = fmaf(w2n[4*c+2], h4.z, axn); axn = fmaf(w2n[4*c+3], h4.w, axn);
                } else {
                    ahn = fmaf(w2n[4*c+0], h4.x, ahn); ahn = fmaf(w2n[4*c+1], h4.y, ahn);
                    ahn = fmaf(w2n[4*c+2], h4.z, ahn); ahn = fmaf(w2n[4*c+3], h4.w, ahn);
                }
            }
        }

        // ---- L1 reduce (quad) + gates (all lanes valid) ----
        ar = dpp_add<0xB1>(ar); ar = dpp_add<0x4E>(ar);
        az = dpp_add<0xB1>(az); az = dpp_add<0x4E>(az);
        an = dpp_add<0xB1>(an); an = dpp_add<0x4E>(an);
        {
            const float r1 = sig_scaled(xr + ar);
            const float z1 = sig_scaled(xz + az);
            const float u1 = fmaf(r1, an + bh1n_s, xn);
            const float n1 = tanh_scaled(u1);
            const float h1old = rp[j1];
            const float h1new = fmaf(z1, h1old - n1, n1);
            if (s1 == 0 && k < T_STEPS) wp[j1] = h1new;
        }
        // ---- L2 reduce (8-lane) + gates ----
        a2r = dpp_add<0xB1>(a2r); a2r = dpp_add<0x4E>(a2r); a2r = swz_add_xor4(a2r);
        a2z = dpp_add<0xB1>(a2z); a2z = dpp_add<0x4E>(a2z); a2z = swz_add_xor4(a2z);
        axn = dpp_add<0xB1>(axn); axn = dpp_add<0x4E>(axn); axn = swz_add_xor4(axn);
        ahn = dpp_add<0xB1>(ahn); ahn = dpp_add<0x4E>(ahn); ahn = swz_add_xor4(ahn);
        {
            const float r2 = sig_scaled(a2r + b2r_s);
            const float z2 = sig_scaled(a2z + b2z_s);
            const float u2 = fmaf(r2, ahn + b2hn_s, axn + b2xn_s);
            const float n2 = tanh_scaled(u2);
            const float h2old = rp[H1 + j2];
            const float h2new = fmaf(z2, h2old - n2, n2);
            if (s2 == 0 && k != 0) {
                wp[H1 + j2] = h2new;
                h2_all[(size_t)(k - 1) * H2 + j2] = h2new;
            }
        }
        __syncthreads();
    }
}

// ---------------------------------------------------------------------------
// Kernel 3: out[t][o] = lin_b[o] + sum_j h2_all[t][j] * lin_w[o][j]
// ---------------------------------------------------------------------------
__global__ __launch_bounds__(256) void head_kernel(
    const float* __restrict__ h2_all,
    const float* __restrict__ lin_w,
    const float* __restrict__ lin_b,
    float* __restrict__ out)
{
    const int t = blockIdx.x * blockDim.x + threadIdx.x;
    if (t >= T_STEPS) return;
    const float* h = h2_all + t * H2;
    #pragma unroll
    for (int o = 0; o < OUT_N; o++) {
        float acc = lin_b[o];
        const float* w = lin_w + o * H2;
        #pragma unroll
        for (int j = 0; j < H2; j += 4) {
            float4 wv = *(const float4*)(w + j);
            float4 hv = *(const float4*)(h + j);
            acc = fmaf(wv.x, hv.x, acc);
            acc = fmaf(wv.y, hv.y, acc);
            acc = fmaf(wv.z, hv.z, acc);
            acc = fmaf(wv.w, hv.w, acc);
        }
        out[t * OUT_N + o] = acc;
    }
}

extern "C" void kernel_launch(void* const* d_in, const int* in_sizes, int n_in,
                              void* d_out, int out_size, void* d_ws, size_t ws_size,
                              hipStream_t stream) {
    const float* x     = (const float*)d_in[0];
    const float* w_ih1 = (const float*)d_in[1];
    const float* w_hh1 = (const float*)d_in[2];
    const float* b_ih1 = (const float*)d_in[3];
    const float* b_hh1 = (const float*)d_in[4];
    const float* w_ih2 = (const float*)d_in[5];
    const float* w_hh2 = (const float*)d_in[6];
    const float* b_ih2 = (const float*)d_in[7];
    const float* b_hh2 = (const float*)d_in[8];
    const float* lin_w = (const float*)d_in[9];
    const float* lin_b = (const float*)d_in[10];
    float* out = (float*)d_out;

    float* xp     = (float*)d_ws;                  // 512*384 floats (pre-scaled)
    float* h2_all = xp + T_STEPS * 3 * H1;         // 512*64 floats

    xp1_kernel<<<T_STEPS, 3 * H1, 0, stream>>>(x, w_ih1, b_ih1, b_hh1, xp);
    gru_seq_kernel<<<1, 512, 0, stream>>>(xp, w_hh1, b_hh1,
                                          w_ih2, b_ih2, w_hh2, b_hh2, h2_all);
    head_kernel<<<(T_STEPS + 255) / 256, 256, 0, stream>>>(h2_all, lin_w, lin_b, out);
}

// Round 3
// 672.720 us; speedup vs baseline: 1.3526x; 1.0266x over previous
//
#include <hip/hip_runtime.h>
#include <hip/hip_bf16.h>

#define T_STEPS 512
#define BATCH   256
#define FDIM    256
#define H1      128
#define H2      64
#define OUT_N   5
#define CAT     (H1 + H2)     // 192
#define LOG2E   1.4426950408889634f

#if __has_builtin(__builtin_amdgcn_exp2f)
#define EXP2F(x) __builtin_amdgcn_exp2f(x)
#else
#define EXP2F(x) exp2f(x)
#endif
#if __has_builtin(__builtin_amdgcn_rcpf)
#define RCPF(x) __builtin_amdgcn_rcpf(x)
#else
#define RCPF(x) (1.0f / (x))
#endif

// v + v(permuted) via DPP. 0xB1 = quad_perm xor1, 0x4E = quad_perm xor2,
// 0x141 = row_half_mirror (valid as xor4-step once quads are uniform).
template<int CTRL>
__device__ __forceinline__ float dpp_add(float v) {
    int s = __builtin_amdgcn_update_dpp(0, __float_as_int(v), CTRL, 0xF, 0xF, true);
    return v + __int_as_float(s);
}
// a = -log2e * x  ->  sigmoid(x)
__device__ __forceinline__ float sig_scaled(float a) {
    return RCPF(1.0f + EXP2F(a));
}
// a = 2*log2e * u ->  tanh(u)   (inf-safe: exp2->inf => rcp->0 => 1)
__device__ __forceinline__ float tanh_scaled(float a) {
    return fmaf(-2.0f, RCPF(EXP2F(a) + 1.0f), 1.0f);
}

// ---------------------------------------------------------------------------
// Kernel 1: xp[t][g] = scale_g * (b_ih1[g] + badd_g + sum_f x[t,255,f]*w_ih1[g,f])
// Quad-per-row K-split: lane s of quad q reads w[g][s*4+16c] -> each quad's
// loads are 64B-contiguous (4x better coalescing than row-per-thread).
// 256 threads, 6 passes of 64 rows. DPP quad reduce.
// ---------------------------------------------------------------------------
__global__ __launch_bounds__(256) void xp1_kernel(
    const float* __restrict__ x,
    const float* __restrict__ w_ih1,
    const float* __restrict__ b_ih1,
    const float* __restrict__ b_hh1,
    float* __restrict__ xp)
{
    __shared__ float xrow[FDIM];
    const int t = blockIdx.x;
    const float* xr = x + (size_t)t * BATCH * FDIM + (size_t)(BATCH - 1) * FDIM;
    if (threadIdx.x < FDIM / 4) {
        ((float4*)xrow)[threadIdx.x] = ((const float4*)xr)[threadIdx.x];
    }
    __syncthreads();
    const int q = threadIdx.x >> 2;
    const int s = threadIdx.x & 3;
    #pragma unroll
    for (int pass = 0; pass < 6; ++pass) {
        const int g = pass * 64 + q;
        const float* w = w_ih1 + (size_t)g * FDIM + (s << 2);
        float acc = 0.0f;
        #pragma unroll
        for (int c = 0; c < 16; ++c) {
            float4 wv = *(const float4*)(w + 16 * c);
            const float* xv = xrow + (s << 2) + 16 * c;
            acc = fmaf(wv.x, xv[0], acc);
            acc = fmaf(wv.y, xv[1], acc);
            acc = fmaf(wv.z, xv[2], acc);
            acc = fmaf(wv.w, xv[3], acc);
        }
        acc = dpp_add<0xB1>(acc);
        acc = dpp_add<0x4E>(acc);
        if (s == 0) {
            const bool isN = (g >= 2 * H1);
            const float badd  = isN ? 0.0f : b_hh1[g];
            const float scale = isN ? (2.0f * LOG2E) : (-LOG2E);
            xp[t * (3 * H1) + g] = scale * (acc + b_ih1[g] + badd);
        }
    }
}

// ---------------------------------------------------------------------------
// Kernel 2: sequential 2-layer GRU, software-pipelined (L1 step k || L2 step
// k-1), ONE barrier per iteration. 512 thr = 8 waves on 1 CU.
// amdgpu_waves_per_eu(2) -> 256-VGPR cap so the 168 weight floats/thread are
// truly register-resident (round-2's (512,2) launch_bounds gave a 128 cap ->
// scratch). Weights pre-scaled by -log2e / 2log2e so gates are exp2+rcp only.
// ---------------------------------------------------------------------------
__global__ __launch_bounds__(512)
__attribute__((amdgpu_waves_per_eu(2)))
void gru_seq_kernel(
    const float* __restrict__ xp,
    const float* __restrict__ w_hh1, const float* __restrict__ b_hh1,
    const float* __restrict__ w_ih2, const float* __restrict__ b_ih2,
    const float* __restrict__ w_hh2, const float* __restrict__ b_hh2,
    float* __restrict__ h2_all)
{
    const int tid = threadIdx.x;
    const int j1 = tid >> 2, s1 = tid & 3;
    const int j2 = tid >> 3, s2 = tid & 7;
    const float sRZ = -LOG2E, sN = 2.0f * LOG2E;

    // ---- L1 weights (scaled), slice k = s1*4 + 16c ----
    float w1r[32], w1z[32], w1n[32];
    {
        const float* br = w_hh1 + (size_t)(         j1) * H1;
        const float* bz = w_hh1 + (size_t)(H1     + j1) * H1;
        const float* bn = w_hh1 + (size_t)(2 * H1 + j1) * H1;
        #pragma unroll
        for (int c = 0; c < 8; c++) {
            const int kk = (s1 << 2) + 16 * c;
            float4 vr = *(const float4*)(br + kk);
            float4 vz = *(const float4*)(bz + kk);
            float4 vn = *(const float4*)(bn + kk);
            w1r[4*c+0] = sRZ*vr.x; w1r[4*c+1] = sRZ*vr.y; w1r[4*c+2] = sRZ*vr.z; w1r[4*c+3] = sRZ*vr.w;
            w1z[4*c+0] = sRZ*vz.x; w1z[4*c+1] = sRZ*vz.y; w1z[4*c+2] = sRZ*vz.z; w1z[4*c+3] = sRZ*vz.w;
            w1n[4*c+0] = sN *vn.x; w1n[4*c+1] = sN *vn.y; w1n[4*c+2] = sN *vn.z; w1n[4*c+3] = sN *vn.w;
        }
    }
    // ---- L2 concat weights (scaled), slice k = s2*4 + 32c over [h1;h2] ----
    float w2r[24], w2z[24], w2n[24];
    {
        const float* ir  = w_ih2 + (size_t)(         j2) * H1;
        const float* iz  = w_ih2 + (size_t)(H2     + j2) * H1;
        const float* inn = w_ih2 + (size_t)(2 * H2 + j2) * H1;
        const float* hr  = w_hh2 + (size_t)(         j2) * H2;
        const float* hz  = w_hh2 + (size_t)(H2     + j2) * H2;
        const float* hn  = w_hh2 + (size_t)(2 * H2 + j2) * H2;
        #pragma unroll
        for (int c = 0; c < 6; c++) {
            const int kk = (s2 << 2) + 32 * c;
            const bool lo = (kk < H1);
            float4 vr = *(const float4*)(lo ? ir  + kk : hr + (kk - H1));
            float4 vz = *(const float4*)(lo ? iz  + kk : hz + (kk - H1));
            float4 vn = *(const float4*)(lo ? inn + kk : hn + (kk - H1));
            w2r[4*c+0] = sRZ*vr.x; w2r[4*c+1] = sRZ*vr.y; w2r[4*c+2] = sRZ*vr.z; w2r[4*c+3] = sRZ*vr.w;
            w2z[4*c+0] = sRZ*vz.x; w2z[4*c+1] = sRZ*vz.y; w2z[4*c+2] = sRZ*vz.z; w2z[4*c+3] = sRZ*vz.w;
            w2n[4*c+0] = sN *vn.x; w2n[4*c+1] = sN *vn.y; w2n[4*c+2] = sN *vn.z; w2n[4*c+3] = sN *vn.w;
        }
    }
    const float bh1n_s = sN * b_hh1[2 * H1 + j1];
    const float b2r_s  = sRZ * (b_ih2[j2]          + b_hh2[j2]);
    const float b2z_s  = sRZ * (b_ih2[H2 + j2]     + b_hh2[H2 + j2]);
    const float b2xn_s = sN  *  b_ih2[2 * H2 + j2];
    const float b2hn_s = sN  *  b_hh2[2 * H2 + j2];

    __shared__ float cat[2][CAT];
    if (tid < CAT) { cat[0][tid] = 0.0f; cat[1][tid] = 0.0f; }

    // prefetch xp row 0
    float cxr = xp[j1], cxz = xp[H1 + j1], cxn = xp[2 * H1 + j1];
    __syncthreads();

    for (int k = 0; k <= T_STEPS; ++k) {
        const int pc = k & 1, pp = pc ^ 1;
        const float* rp = cat[pp];
        float* wp = cat[pc];

        const float xr = cxr, xz = cxz, xn = cxn;
        if (k + 1 < T_STEPS) {
            const float* nx = xp + (size_t)(k + 1) * (3 * H1);
            cxr = nx[j1]; cxz = nx[H1 + j1]; cxn = nx[2 * H1 + j1];
        }

        // ---------------- L1: h1[k] = f(h1[k-1], xp[k]) ----------------
        float ar = 0.f, az = 0.f, an = 0.f;
        {
            const float* hp = rp + (s1 << 2);
            #pragma unroll
            for (int c = 0; c < 8; c++) {
                float4 h4 = *(const float4*)(hp + 16 * c);
                ar = fmaf(w1r[4*c+0], h4.x, ar); az = fmaf(w1z[4*c+0], h4.x, az); an = fmaf(w1n[4*c+0], h4.x, an);
                ar = fmaf(w1r[4*c+1], h4.y, ar); az = fmaf(w1z[4*c+1], h4.y, az); an = fmaf(w1n[4*c+1], h4.y, an);
                ar = fmaf(w1r[4*c+2], h4.z, ar); az = fmaf(w1z[4*c+2], h4.z, az); an = fmaf(w1n[4*c+2], h4.z, an);
                ar = fmaf(w1r[4*c+3], h4.w, ar); az = fmaf(w1z[4*c+3], h4.w, az); an = fmaf(w1n[4*c+3], h4.w, an);
            }
        }
        // ---------------- L2: h2[k-1] = g(h2[k-2], h1[k-1]) ------------
        float a2r = 0.f, a2z = 0.f, axn = 0.f, ahn = 0.f;
        {
            const float* gp = rp + (s2 << 2);
            #pragma unroll
            for (int c = 0; c < 6; c++) {
                float4 h4 = *(const float4*)(gp + 32 * c);
                a2r = fmaf(w2r[4*c+0], h4.x, a2r); a2z = fmaf(w2z[4*c+0], h4.x, a2z);
                a2r = fmaf(w2r[4*c+1], h4.y, a2r); a2z = fmaf(w2z[4*c+1], h4.y, a2z);
                a2r = fmaf(w2r[4*c+2], h4.z, a2r); a2z = fmaf(w2z[4*c+2], h4.z, a2z);
                a2r = fmaf(w2r[4*c+3], h4.w, a2r); a2z = fmaf(w2z[4*c+3], h4.w, a2z);
                if (c < 4) {
                    axn = fmaf(w2n[4*c+0], h4.x, axn); axn = fmaf(w2n[4*c+1], h4.y, axn);
                    axn = fmaf(w2n[4*c+2], h4.z, axn); axn = fmaf(w2n[4*c+3], h4.w, axn);
                } else {
                    ahn = fmaf(w2n[4*c+0], h4.x, ahn); ahn = fmaf(w2n[4*c+1], h4.y, ahn);
                    ahn = fmaf(w2n[4*c+2], h4.z, ahn); ahn = fmaf(w2n[4*c+3], h4.w, ahn);
                }
            }
        }

        // ---- L1 reduce (quad) + gates (all lanes valid) ----
        ar = dpp_add<0xB1>(ar); ar = dpp_add<0x4E>(ar);
        az = dpp_add<0xB1>(az); az = dpp_add<0x4E>(az);
        an = dpp_add<0xB1>(an); an = dpp_add<0x4E>(an);
        {
            const float r1 = sig_scaled(xr + ar);
            const float z1 = sig_scaled(xz + az);
            const float u1 = fmaf(r1, an + bh1n_s, xn);
            const float n1 = tanh_scaled(u1);
            const float h1old = rp[j1];
            const float h1new = fmaf(z1, h1old - n1, n1);
            if (s1 == 0 && k < T_STEPS) wp[j1] = h1new;
        }
        // ---- L2 reduce (8-lane, pure DPP) + gates ----
        a2r = dpp_add<0xB1>(a2r); a2r = dpp_add<0x4E>(a2r); a2r = dpp_add<0x141>(a2r);
        a2z = dpp_add<0xB1>(a2z); a2z = dpp_add<0x4E>(a2z); a2z = dpp_add<0x141>(a2z);
        axn = dpp_add<0xB1>(axn); axn = dpp_add<0x4E>(axn); axn = dpp_add<0x141>(axn);
        ahn = dpp_add<0xB1>(ahn); ahn = dpp_add<0x4E>(ahn); ahn = dpp_add<0x141>(ahn);
        {
            const float r2 = sig_scaled(a2r + b2r_s);
            const float z2 = sig_scaled(a2z + b2z_s);
            const float u2 = fmaf(r2, ahn + b2hn_s, axn + b2xn_s);
            const float n2 = tanh_scaled(u2);
            const float h2old = rp[H1 + j2];
            const float h2new = fmaf(z2, h2old - n2, n2);
            if (s2 == 0 && k != 0) {
                wp[H1 + j2] = h2new;
                h2_all[(size_t)(k - 1) * H2 + j2] = h2new;
            }
        }
        __syncthreads();
    }
}

// ---------------------------------------------------------------------------
// Kernel 3: out[t][o] = lin_b[o] + sum_j h2_all[t][j] * lin_w[o][j]
// ---------------------------------------------------------------------------
__global__ __launch_bounds__(256) void head_kernel(
    const float* __restrict__ h2_all,
    const float* __restrict__ lin_w,
    const float* __restrict__ lin_b,
    float* __restrict__ out)
{
    const int t = blockIdx.x * blockDim.x + threadIdx.x;
    if (t >= T_STEPS) return;
    const float* h = h2_all + t * H2;
    #pragma unroll
    for (int o = 0; o < OUT_N; o++) {
        float acc = lin_b[o];
        const float* w = lin_w + o * H2;
        #pragma unroll
        for (int j = 0; j < H2; j += 4) {
            float4 wv = *(const float4*)(w + j);
            float4 hv = *(const float4*)(h + j);
            acc = fmaf(wv.x, hv.x, acc);
            acc = fmaf(wv.y, hv.y, acc);
            acc = fmaf(wv.z, hv.z, acc);
            acc = fmaf(wv.w, hv.w, acc);
        }
        out[t * OUT_N + o] = acc;
    }
}

extern "C" void kernel_launch(void* const* d_in, const int* in_sizes, int n_in,
                              void* d_out, int out_size, void* d_ws, size_t ws_size,
                              hipStream_t stream) {
    const float* x     = (const float*)d_in[0];
    const float* w_ih1 = (const float*)d_in[1];
    const float* w_hh1 = (const float*)d_in[2];
    const float* b_ih1 = (const float*)d_in[3];
    const float* b_hh1 = (const float*)d_in[4];
    const float* w_ih2 = (const float*)d_in[5];
    const float* w_hh2 = (const float*)d_in[6];
    const float* b_ih2 = (const float*)d_in[7];
    const float* b_hh2 = (const float*)d_in[8];
    const float* lin_w = (const float*)d_in[9];
    const float* lin_b = (const float*)d_in[10];
    float* out = (float*)d_out;

    float* xp     = (float*)d_ws;                  // 512*384 floats (pre-scaled)
    float* h2_all = xp + T_STEPS * 3 * H1;         // 512*64 floats

    xp1_kernel<<<T_STEPS, 256, 0, stream>>>(x, w_ih1, b_ih1, b_hh1, xp);
    gru_seq_kernel<<<1, 512, 0, stream>>>(xp, w_hh1, b_hh1,
                                          w_ih2, b_ih2, w_hh2, b_hh2, h2_all);
    head_kernel<<<(T_STEPS + 255) / 256, 256, 0, stream>>>(h2_all, lin_w, lin_b, out);
}

// Round 5
// 542.774 us; speedup vs baseline: 1.6765x; 1.2394x over previous
//
#include <hip/hip_runtime.h>
#include <hip/hip_bf16.h>

#define T_STEPS 512
#define BATCH   256
#define FDIM    256
#define H1      128
#define H2      64
#define OUT_N   5
#define CAT     (H1 + H2)     // 192
#define LOG2E   1.4426950408889634f

#if __has_builtin(__builtin_amdgcn_exp2f)
#define EXP2F(x) __builtin_amdgcn_exp2f(x)
#else
#define EXP2F(x) exp2f(x)
#endif
#if __has_builtin(__builtin_amdgcn_rcpf)
#define RCPF(x) __builtin_amdgcn_rcpf(x)
#else
#define RCPF(x) (1.0f / (x))
#endif

// v + v(permuted) via DPP. 0xB1 = quad_perm xor1, 0x4E = quad_perm xor2,
// 0x141 = row_half_mirror (valid as xor4-step once quads are uniform).
template<int CTRL>
__device__ __forceinline__ float dpp_add(float v) {
    int s = __builtin_amdgcn_update_dpp(0, __float_as_int(v), CTRL, 0xF, 0xF, true);
    return v + __int_as_float(s);
}
// a = -log2e * x  ->  sigmoid(x)
__device__ __forceinline__ float sig_scaled(float a) {
    return RCPF(1.0f + EXP2F(a));
}
// a = 2*log2e * u ->  tanh(u)   (inf-safe: exp2->inf => rcp->0 => 1)
__device__ __forceinline__ float tanh_scaled(float a) {
    return fmaf(-2.0f, RCPF(EXP2F(a) + 1.0f), 1.0f);
}

// ---------------------------------------------------------------------------
// Kernel 1: xp[t][g] = scale_g * (b_ih1[g] + badd_g + sum_f x[t,255,f]*w_ih1[g,f])
// Quad-per-row K-split; DPP quad reduce. badd folds b_hh1 for r,z.
// ---------------------------------------------------------------------------
__global__ __launch_bounds__(256) void xp1_kernel(
    const float* __restrict__ x,
    const float* __restrict__ w_ih1,
    const float* __restrict__ b_ih1,
    const float* __restrict__ b_hh1,
    float* __restrict__ xp)
{
    __shared__ float xrow[FDIM];
    const int t = blockIdx.x;
    const float* xr = x + (size_t)t * BATCH * FDIM + (size_t)(BATCH - 1) * FDIM;
    if (threadIdx.x < FDIM / 4) {
        ((float4*)xrow)[threadIdx.x] = ((const float4*)xr)[threadIdx.x];
    }
    __syncthreads();
    const int q = threadIdx.x >> 2;
    const int s = threadIdx.x & 3;
    #pragma unroll
    for (int pass = 0; pass < 6; ++pass) {
        const int g = pass * 64 + q;
        const float* w = w_ih1 + (size_t)g * FDIM + (s << 2);
        float acc = 0.0f;
        #pragma unroll
        for (int c = 0; c < 16; ++c) {
            float4 wv = *(const float4*)(w + 16 * c);
            const float* xv = xrow + (s << 2) + 16 * c;
            acc = fmaf(wv.x, xv[0], acc);
            acc = fmaf(wv.y, xv[1], acc);
            acc = fmaf(wv.z, xv[2], acc);
            acc = fmaf(wv.w, xv[3], acc);
        }
        acc = dpp_add<0xB1>(acc);
        acc = dpp_add<0x4E>(acc);
        if (s == 0) {
            const bool isN = (g >= 2 * H1);
            const float badd  = isN ? 0.0f : b_hh1[g];
            const float scale = isN ? (2.0f * LOG2E) : (-LOG2E);
            xp[t * (3 * H1) + g] = scale * (acc + b_ih1[g] + badd);
        }
    }
}

// ---------------------------------------------------------------------------
// Kernel 2: sequential 2-layer GRU, wave-specialized.
// 1024 threads = 16 waves on 1 CU. Waves 0-7 (tid<512) = layer 1 only
// (4 lanes/row, 96 weight floats); waves 8-15 = layer 2 only (8 lanes/row,
// 72 weight floats). Disjoint code regions keep peak VGPR pressure ~125
// (< the 128 cap at 4 waves/SIMD) so weights are truly register-resident
// with NO AGPR round-trips (round-3's 512-thr layout needed 168/thread and
// the allocator AGPR-spilled them: +~170 VALU copies/iter).
// Software-pipelined: at step k, L1 makes h1[k] while L2 makes h2[k-1];
// both read only cat_prev, write only cat_cur -> one barrier per step.
// Each branch executes exactly 514 barriers.
// ---------------------------------------------------------------------------
__global__ __launch_bounds__(1024) void gru_seq_kernel(
    const float* __restrict__ xp,
    const float* __restrict__ w_hh1, const float* __restrict__ b_hh1,
    const float* __restrict__ w_ih2, const float* __restrict__ b_ih2,
    const float* __restrict__ w_hh2, const float* __restrict__ b_hh2,
    float* __restrict__ h2_all)
{
    const int tid = threadIdx.x;
    __shared__ float cat0[CAT];   // [h1(128); h2(64)], written at even k
    __shared__ float cat1[CAT];   // written at odd k
    if (tid < CAT) { cat0[tid] = 0.0f; cat1[tid] = 0.0f; }

    const float sRZ = -LOG2E, sN = 2.0f * LOG2E;

    if (tid < 512) {
        // ================= LAYER-1 WAVES =================
        const int j1 = tid >> 2, s1 = tid & 3;
        float w1r[32], w1z[32], w1n[32];
        {
            const float* br = w_hh1 + (size_t)(         j1) * H1;
            const float* bz = w_hh1 + (size_t)(H1     + j1) * H1;
            const float* bn = w_hh1 + (size_t)(2 * H1 + j1) * H1;
            #pragma unroll
            for (int c = 0; c < 8; c++) {
                const int kk = (s1 << 2) + 16 * c;
                float4 vr = *(const float4*)(br + kk);
                float4 vz = *(const float4*)(bz + kk);
                float4 vn = *(const float4*)(bn + kk);
                w1r[4*c+0]=sRZ*vr.x; w1r[4*c+1]=sRZ*vr.y; w1r[4*c+2]=sRZ*vr.z; w1r[4*c+3]=sRZ*vr.w;
                w1z[4*c+0]=sRZ*vz.x; w1z[4*c+1]=sRZ*vz.y; w1z[4*c+2]=sRZ*vz.z; w1z[4*c+3]=sRZ*vz.w;
                w1n[4*c+0]=sN *vn.x; w1n[4*c+1]=sN *vn.y; w1n[4*c+2]=sN *vn.z; w1n[4*c+3]=sN *vn.w;
            }
        }
        const float bh1n_s = sN * b_hh1[2 * H1 + j1];
        const float* xq = xp + j1;
        float cxr = xq[0], cxz = xq[H1], cxn = xq[2 * H1];
        xq += 3 * H1;
        __syncthreads();                       // [1] init visible

        // ---- k = 0 (h1_prev = 0: matvec terms vanish) ----
        {
            float nr = xq[0], nz = xq[H1], nn = xq[2 * H1]; xq += 3 * H1;
            const float r1 = sig_scaled(cxr);
            const float z1 = sig_scaled(cxz);
            const float n1 = tanh_scaled(fmaf(r1, bh1n_s, cxn));
            if (s1 == 0) cat0[j1] = (1.0f - z1) * n1;
            cxr = nr; cxz = nz; cxn = nn;
            __syncthreads();                   // [2] k=0
        }

        #define L1_STEP(RP, WP, PREF) do {                                              \
            const float* hp = RP + (s1 << 2);                                           \
            float ar = 0.f, az = 0.f, an = 0.f;                                         \
            _Pragma("unroll")                                                           \
            for (int c = 0; c < 8; c++) {                                               \
                float4 h4 = *(const float4*)(hp + 16 * c);                              \
                ar=fmaf(w1r[4*c+0],h4.x,ar); az=fmaf(w1z[4*c+0],h4.x,az); an=fmaf(w1n[4*c+0],h4.x,an); \
                ar=fmaf(w1r[4*c+1],h4.y,ar); az=fmaf(w1z[4*c+1],h4.y,az); an=fmaf(w1n[4*c+1],h4.y,an); \
                ar=fmaf(w1r[4*c+2],h4.z,ar); az=fmaf(w1z[4*c+2],h4.z,az); an=fmaf(w1n[4*c+2],h4.z,an); \
                ar=fmaf(w1r[4*c+3],h4.w,ar); az=fmaf(w1z[4*c+3],h4.w,az); an=fmaf(w1n[4*c+3],h4.w,an); \
            }                                                                           \
            const float h1old = RP[j1];                                                 \
            float nr = 0.f, nz = 0.f, nn = 0.f;                                         \
            if (PREF) { nr = xq[0]; nz = xq[H1]; nn = xq[2 * H1]; xq += 3 * H1; }       \
            ar = dpp_add<0xB1>(ar); ar = dpp_add<0x4E>(ar);                             \
            az = dpp_add<0xB1>(az); az = dpp_add<0x4E>(az);                             \
            an = dpp_add<0xB1>(an); an = dpp_add<0x4E>(an);                             \
            const float r1 = sig_scaled(cxr + ar);                                      \
            const float z1 = sig_scaled(cxz + az);                                      \
            const float n1 = tanh_scaled(fmaf(r1, an + bh1n_s, cxn));                   \
            if (s1 == 0) WP[j1] = fmaf(z1, h1old - n1, n1);                             \
            cxr = nr; cxz = nz; cxn = nn;                                               \
        } while (0)

        #pragma unroll 1
        for (int i = 0; i < 255; i++) {        // k = 2i+1, 2i+2  (1..510)
            L1_STEP(cat0, cat1, true);
            __syncthreads();
            L1_STEP(cat1, cat0, true);
            __syncthreads();
        }
        L1_STEP(cat0, cat1, false);            // k = 511
        __syncthreads();
        __syncthreads();                       // k = 512 (L2's last step)
        #undef L1_STEP
    } else {
        // ================= LAYER-2 WAVES =================
        const int t2 = tid - 512;
        const int j2 = t2 >> 3, s2 = t2 & 7;
        // concat weights over [h1(128); h2(64)], slice k = s2*4 + 32c:
        // c<4 -> x-part (w_ih2), c=4,5 -> h-part (w_hh2).
        float w2r[24], w2z[24], w2n[24];
        {
            const float* ir  = w_ih2 + (size_t)(         j2) * H1;
            const float* iz  = w_ih2 + (size_t)(H2     + j2) * H1;
            const float* inn = w_ih2 + (size_t)(2 * H2 + j2) * H1;
            #pragma unroll
            for (int c = 0; c < 4; c++) {
                const int kk = (s2 << 2) + 32 * c;
                float4 vr = *(const float4*)(ir  + kk);
                float4 vz = *(const float4*)(iz  + kk);
                float4 vn = *(const float4*)(inn + kk);
                w2r[4*c+0]=sRZ*vr.x; w2r[4*c+1]=sRZ*vr.y; w2r[4*c+2]=sRZ*vr.z; w2r[4*c+3]=sRZ*vr.w;
                w2z[4*c+0]=sRZ*vz.x; w2z[4*c+1]=sRZ*vz.y; w2z[4*c+2]=sRZ*vz.z; w2z[4*c+3]=sRZ*vz.w;
                w2n[4*c+0]=sN *vn.x; w2n[4*c+1]=sN *vn.y; w2n[4*c+2]=sN *vn.z; w2n[4*c+3]=sN *vn.w;
            }
            const float* hr = w_hh2 + (size_t)(         j2) * H2;
            const float* hz = w_hh2 + (size_t)(H2     + j2) * H2;
            const float* hn = w_hh2 + (size_t)(2 * H2 + j2) * H2;
            #pragma unroll
            for (int c = 0; c < 2; c++) {
                const int kk = (s2 << 2) + 32 * c;
                const int o = 4 * (c + 4);
                float4 vr = *(const float4*)(hr + kk);
                float4 vz = *(const float4*)(hz + kk);
                float4 vn = *(const float4*)(hn + kk);
                w2r[o+0]=sRZ*vr.x; w2r[o+1]=sRZ*vr.y; w2r[o+2]=sRZ*vr.z; w2r[o+3]=sRZ*vr.w;
                w2z[o+0]=sRZ*vz.x; w2z[o+1]=sRZ*vz.y; w2z[o+2]=sRZ*vz.z; w2z[o+3]=sRZ*vz.w;
                w2n[o+0]=sN *vn.x; w2n[o+1]=sN *vn.y; w2n[o+2]=sN *vn.z; w2n[o+3]=sN *vn.w;
            }
        }
        const float b2r_s  = sRZ * (b_ih2[j2]      + b_hh2[j2]);
        const float b2z_s  = sRZ * (b_ih2[H2 + j2] + b_hh2[H2 + j2]);
        const float b2xn_s = sN  *  b_ih2[2 * H2 + j2];
        const float b2hn_s = sN  *  b_hh2[2 * H2 + j2];
        float* hout = h2_all + j2;
        __syncthreads();                       // [1] init visible
        __syncthreads();                       // [2] k=0 (no L2 work)

        #define L2_STEP(RP, WP) do {                                                    \
            const float* gp = RP + (s2 << 2);                                           \
            float a2r = 0.f, a2z = 0.f, axn = 0.f, ahn = 0.f;                           \
            _Pragma("unroll")                                                           \
            for (int c = 0; c < 4; c++) {                                               \
                float4 g4 = *(const float4*)(gp + 32 * c);                              \
                a2r=fmaf(w2r[4*c+0],g4.x,a2r); a2z=fmaf(w2z[4*c+0],g4.x,a2z); axn=fmaf(w2n[4*c+0],g4.x,axn); \
                a2r=fmaf(w2r[4*c+1],g4.y,a2r); a2z=fmaf(w2z[4*c+1],g4.y,a2z); axn=fmaf(w2n[4*c+1],g4.y,axn); \
                a2r=fmaf(w2r[4*c+2],g4.z,a2r); a2z=fmaf(w2z[4*c+2],g4.z,a2z); axn=fmaf(w2n[4*c+2],g4.z,axn); \
                a2r=fmaf(w2r[4*c+3],g4.w,a2r); a2z=fmaf(w2z[4*c+3],g4.w,a2z); axn=fmaf(w2n[4*c+3],g4.w,axn); \
            }                                                                           \
            _Pragma("unroll")                                                           \
            for (int c = 4; c < 6; c++) {                                               \
                float4 g4 = *(const float4*)(gp + 32 * c);                              \
                a2r=fmaf(w2r[4*c+0],g4.x,a2r); a2z=fmaf(w2z[4*c+0],g4.x,a2z); ahn=fmaf(w2n[4*c+0],g4.x,ahn); \
                a2r=fmaf(w2r[4*c+1],g4.y,a2r); a2z=fmaf(w2z[4*c+1],g4.y,a2z); ahn=fmaf(w2n[4*c+1],g4.y,ahn); \
                a2r=fmaf(w2r[4*c+2],g4.z,a2r); a2z=fmaf(w2z[4*c+2],g4.z,a2z); ahn=fmaf(w2n[4*c+2],g4.z,ahn); \
                a2r=fmaf(w2r[4*c+3],g4.w,a2r); a2z=fmaf(w2z[4*c+3],g4.w,a2z); ahn=fmaf(w2n[4*c+3],g4.w,ahn); \
            }                                                                           \
            const float h2old = RP[H1 + j2];                                            \
            a2r = dpp_add<0xB1>(a2r); a2r = dpp_add<0x4E>(a2r); a2r = dpp_add<0x141>(a2r); \
            a2z = dpp_add<0xB1>(a2z); a2z = dpp_add<0x4E>(a2z); a2z = dpp_add<0x141>(a2z); \
            axn = dpp_add<0xB1>(axn); axn = dpp_add<0x4E>(axn); axn = dpp_add<0x141>(axn); \
            ahn = dpp_add<0xB1>(ahn); ahn = dpp_add<0x4E>(ahn); ahn = dpp_add<0x141>(ahn); \
            const float r2 = sig_scaled(a2r + b2r_s);                                   \
            const float z2 = sig_scaled(a2z + b2z_s);                                   \
            const float n2 = tanh_scaled(fmaf(r2, ahn + b2hn_s, axn + b2xn_s));         \
            const float h2new = fmaf(z2, h2old - n2, n2);                               \
            if (s2 == 0) { WP[H1 + j2] = h2new; *hout = h2new; }                        \
            hout += H2;                                                                 \
        } while (0)

        #pragma unroll 1
        for (int i = 0; i < 255; i++) {        // k = 2i+1, 2i+2 -> h2[0..509]
            L2_STEP(cat0, cat1);
            __syncthreads();
            L2_STEP(cat1, cat0);
            __syncthreads();
        }
        L2_STEP(cat0, cat1);                   // k = 511 -> h2[510]
        __syncthreads();
        L2_STEP(cat1, cat0);                   // k = 512 -> h2[511]
        __syncthreads();
        #undef L2_STEP
    }
}

// ---------------------------------------------------------------------------
// Kernel 3: out[t][o] = lin_b[o] + sum_j h2_all[t][j] * lin_w[o][j]
// ---------------------------------------------------------------------------
__global__ __launch_bounds__(256) void head_kernel(
    const float* __restrict__ h2_all,
    const float* __restrict__ lin_w,
    const float* __restrict__ lin_b,
    float* __restrict__ out)
{
    const int t = blockIdx.x * blockDim.x + threadIdx.x;
    if (t >= T_STEPS) return;
    const float* h = h2_all + t * H2;
    #pragma unroll
    for (int o = 0; o < OUT_N; o++) {
        float acc = lin_b[o];
        const float* w = lin_w + o * H2;
        #pragma unroll
        for (int j = 0; j < H2; j += 4) {
            float4 wv = *(const float4*)(w + j);
            float4 hv = *(const float4*)(h + j);
            acc = fmaf(wv.x, hv.x, acc);
            acc = fmaf(wv.y, hv.y, acc);
            acc = fmaf(wv.z, hv.z, acc);
            acc = fmaf(wv.w, hv.w, acc);
        }
        out[t * OUT_N + o] = acc;
    }
}

extern "C" void kernel_launch(void* const* d_in, const int* in_sizes, int n_in,
                              void* d_out, int out_size, void* d_ws, size_t ws_size,
                              hipStream_t stream) {
    const float* x     = (const float*)d_in[0];
    const float* w_ih1 = (const float*)d_in[1];
    const float* w_hh1 = (const float*)d_in[2];
    const float* b_ih1 = (const float*)d_in[3];
    const float* b_hh1 = (const float*)d_in[4];
    const float* w_ih2 = (const float*)d_in[5];
    const float* w_hh2 = (const float*)d_in[6];
    const float* b_ih2 = (const float*)d_in[7];
    const float* b_hh2 = (const float*)d_in[8];
    const float* lin_w = (const float*)d_in[9];
    const float* lin_b = (const float*)d_in[10];
    float* out = (float*)d_out;

    float* xp     = (float*)d_ws;                  // 512*384 floats (pre-scaled)
    float* h2_all = xp + T_STEPS * 3 * H1;         // 512*64 floats

    xp1_kernel<<<T_STEPS, 256, 0, stream>>>(x, w_ih1, b_ih1, b_hh1, xp);
    gru_seq_kernel<<<1, 1024, 0, stream>>>(xp, w_hh1, b_hh1,
                                           w_ih2, b_ih2, w_hh2, b_hh2, h2_all);
    head_kernel<<<(T_STEPS + 255) / 256, 256, 0, stream>>>(h2_all, lin_w, lin_b, out);
}